// Round 21
// baseline (990.830 us; speedup 1.0000x reference)
//
#include <hip/hip_runtime.h>

// ---------------------------------------------------------------------------
// CompGCN-style network. MFMA split-bf16 (hi/lo, 3-term) GEMMs.
// Round 21: score q-loads made VOLATILE — the legal pin. LLVM may not remat
// or duplicate a volatile access, so the 28x16B q loads at kernel top stay
// live in VGPRs (~200, within the 256 limit; LDS is the occupancy binder).
// r8/r10 plain+clobber remat'd (VGPR 88); r11 asm-load crashed (untracked
// vmcnt); volatile keeps compiler waitcnt tracking. Rest frozen at r20.
//   N=100000 ents, E=400000 edges, D=200, D0=100, NREL=475, B=1024, L=2
// ---------------------------------------------------------------------------

#define N_ENT  100000
#define N_EDGE 400000
#define D_     200
#define D0_    100
#define NREL_  475
#define B_     1024
#define KP_D   224   // D padded to multiple of 32
#define KP_D0  128   // D0 padded

typedef unsigned short ushort_t;
typedef __attribute__((ext_vector_type(8))) short bf16x8;
typedef __attribute__((ext_vector_type(4))) float f32x4;

__device__ __forceinline__ ushort_t f2bf(float x) {
  unsigned u = __float_as_uint(x);
  return (ushort_t)((u + 0x7FFFu + ((u >> 16) & 1u)) >> 16);
}
__device__ __forceinline__ float bf2f(ushort_t h) {
  return __uint_as_float(((unsigned)h) << 16);
}

__device__ __forceinline__ void gld16(const void* g, void* l) {
  __builtin_amdgcn_global_load_lds(
      (const __attribute__((address_space(1))) unsigned*)g,
      (__attribute__((address_space(3))) unsigned*)l, 16, 0, 0);
}

// ---------------- CSR build (real edges only; self-loops streamed) ----------

__global__ void k_hist(const int* __restrict__ dst_id, int* __restrict__ cnt) {
  int e = blockIdx.x * 256 + threadIdx.x;
  if (e < N_EDGE) atomicAdd(&cnt[dst_id[e]], 1);
}

__global__ __launch_bounds__(256) void k_scan_block(const int* __restrict__ cnt,
                                                    int* __restrict__ rp,
                                                    int* __restrict__ bsum) {
  __shared__ int sm[256];
  int tid = threadIdx.x;
  int base = blockIdx.x * 1024 + tid * 4;
  int v0 = (base + 0 < N_ENT) ? cnt[base + 0] : 0;
  int v1 = (base + 1 < N_ENT) ? cnt[base + 1] : 0;
  int v2 = (base + 2 < N_ENT) ? cnt[base + 2] : 0;
  int v3 = (base + 3 < N_ENT) ? cnt[base + 3] : 0;
  int tsum = v0 + v1 + v2 + v3;
  sm[tid] = tsum;
  __syncthreads();
  for (int off = 1; off < 256; off <<= 1) {
    int t = (tid >= off) ? sm[tid - off] : 0;
    __syncthreads();
    sm[tid] += t;
    __syncthreads();
  }
  int run = sm[tid] - tsum;
  if (base + 0 < N_ENT) { rp[base + 0] = run; } run += v0;
  if (base + 1 < N_ENT) { rp[base + 1] = run; } run += v1;
  if (base + 2 < N_ENT) { rp[base + 2] = run; } run += v2;
  if (base + 3 < N_ENT) { rp[base + 3] = run; }
  if (tid == 255) bsum[blockIdx.x] = sm[255];
}

__global__ void k_scan_tops(int* __restrict__ bsum, int nb) {
  __shared__ int sm[256];
  int tid = threadIdx.x;
  int v = (tid < nb) ? bsum[tid] : 0;
  sm[tid] = v;
  __syncthreads();
  for (int off = 1; off < 256; off <<= 1) {
    int t = (tid >= off) ? sm[tid - off] : 0;
    __syncthreads();
    sm[tid] += t;
    __syncthreads();
  }
  if (tid < nb) bsum[tid] = sm[tid] - v;
}

__global__ void k_scan_add(int* __restrict__ rp, const int* __restrict__ bsum,
                           int* __restrict__ cursor) {
  int i = blockIdx.x * 256 + threadIdx.x;
  if (i < N_ENT) {
    int r = rp[i] + bsum[i >> 10];
    rp[i] = r;
    cursor[i] = r;
  }
}

__global__ void k_fill(const int* __restrict__ src_id, const int* __restrict__ dst_id,
                       const int* __restrict__ e_type, int* __restrict__ cursor,
                       int* __restrict__ cs, int* __restrict__ ct) {
  int e = blockIdx.x * 256 + threadIdx.x;
  if (e < N_EDGE) {
    int pos = atomicAdd(&cursor[dst_id[e]], 1);
    cs[pos] = src_id[e];
    ct[pos] = e_type[e];
  }
}

// ---------------- aggregation (fused column stats) ----------------

template <bool BN>
__global__ __launch_bounds__(256) void k_aggregate(const float* __restrict__ ent,
                                                   const float* __restrict__ relE,
                                                   const int* __restrict__ rp,
                                                   const int* __restrict__ cnt,
                                                   const int* __restrict__ cs,
                                                   const int* __restrict__ ct,
                                                   float* __restrict__ out,
                                                   const float* __restrict__ scale,
                                                   const float* __restrict__ shift,
                                                   double* __restrict__ pstat) {
  __shared__ double sred[4 * 200];
  __shared__ double qred[4 * 200];
  const int wv = threadIdx.x >> 6;
  const int lane = threadIdx.x & 63;
  const int f4 = lane * 4;
  double sa[4] = {0, 0, 0, 0}, qa[4] = {0, 0, 0, 0};

  if (lane < 50) {
    float sc[4] = {0, 0, 0, 0}, sh[4] = {0, 0, 0, 0};
    if (BN) {
      float4 s4 = *(const float4*)(scale + f4);
      float4 h4 = *(const float4*)(shift + f4);
      sc[0] = s4.x; sc[1] = s4.y; sc[2] = s4.z; sc[3] = s4.w;
      sh[0] = h4.x; sh[1] = h4.y; sh[2] = h4.z; sh[3] = h4.w;
    }
    float4 rself = *(const float4*)(relE + (long)(NREL_ - 1) * D_ + f4);
    float rs[4] = {rself.x, rself.y, rself.z, rself.w};

    for (int t = 0; t < 16; ++t) {
      int n = blockIdx.x * 64 + wv * 16 + t;
      if (n >= N_ENT) break;

      float ax[4], ay[4] = {0, 0, 0, 0}, az[4] = {0, 0, 0, 0}, aw[4] = {0, 0, 0, 0};
      {
        float4 e = *(const float4*)(ent + (long)n * D_ + f4);
        float ee[4] = {e.x, e.y, e.z, e.w};
#pragma unroll
        for (int u = 0; u < 4; ++u) {
          if (BN) ee[u] = fmaxf(fmaf(ee[u], sc[u], sh[u]), 0.f);
          ax[u] = ee[u] * rs[u];
        }
      }

      int s0 = rp[n], e0 = s0 + cnt[n];
      int idx = s0;
      for (; idx + 4 <= e0; idx += 4) {
        int sA = cs[idx + 0], tA = ct[idx + 0];
        int sB = cs[idx + 1], tB = ct[idx + 1];
        int sC = cs[idx + 2], tC = ct[idx + 2];
        int sD = cs[idx + 3], tD = ct[idx + 3];
        float4 eA = *(const float4*)(ent + (long)sA * D_ + f4);
        float4 eB = *(const float4*)(ent + (long)sB * D_ + f4);
        float4 eC = *(const float4*)(ent + (long)sC * D_ + f4);
        float4 eD = *(const float4*)(ent + (long)sD * D_ + f4);
        float4 rA = *(const float4*)(relE + (long)tA * D_ + f4);
        float4 rB = *(const float4*)(relE + (long)tB * D_ + f4);
        float4 rC = *(const float4*)(relE + (long)tC * D_ + f4);
        float4 rD = *(const float4*)(relE + (long)tD * D_ + f4);
        float ea[4] = {eA.x, eA.y, eA.z, eA.w}, ra[4] = {rA.x, rA.y, rA.z, rA.w};
        float eb[4] = {eB.x, eB.y, eB.z, eB.w}, rb[4] = {rB.x, rB.y, rB.z, rB.w};
        float ec[4] = {eC.x, eC.y, eC.z, eC.w}, rc[4] = {rC.x, rC.y, rC.z, rC.w};
        float ed[4] = {eD.x, eD.y, eD.z, eD.w}, rd[4] = {rD.x, rD.y, rD.z, rD.w};
#pragma unroll
        for (int u = 0; u < 4; ++u) {
          if (BN) {
            ea[u] = fmaxf(fmaf(ea[u], sc[u], sh[u]), 0.f);
            eb[u] = fmaxf(fmaf(eb[u], sc[u], sh[u]), 0.f);
            ec[u] = fmaxf(fmaf(ec[u], sc[u], sh[u]), 0.f);
            ed[u] = fmaxf(fmaf(ed[u], sc[u], sh[u]), 0.f);
          }
          ax[u] = fmaf(ea[u], ra[u], ax[u]);
          ay[u] = fmaf(eb[u], rb[u], ay[u]);
          az[u] = fmaf(ec[u], rc[u], az[u]);
          aw[u] = fmaf(ed[u], rd[u], aw[u]);
        }
      }
      for (; idx < e0; ++idx) {
        int sA = cs[idx], tA = ct[idx];
        float4 eA = *(const float4*)(ent + (long)sA * D_ + f4);
        float4 rA = *(const float4*)(relE + (long)tA * D_ + f4);
        float ea[4] = {eA.x, eA.y, eA.z, eA.w}, ra[4] = {rA.x, rA.y, rA.z, rA.w};
#pragma unroll
        for (int u = 0; u < 4; ++u) {
          if (BN) ea[u] = fmaxf(fmaf(ea[u], sc[u], sh[u]), 0.f);
          ax[u] = fmaf(ea[u], ra[u], ax[u]);
        }
      }
      float o[4];
#pragma unroll
      for (int u = 0; u < 4; ++u) {
        o[u] = (ax[u] + ay[u]) + (az[u] + aw[u]);
        sa[u] += o[u];
        qa[u] += (double)o[u] * o[u];
      }
      *(float4*)(out + (long)n * D_ + f4) = make_float4(o[0], o[1], o[2], o[3]);
    }
  }

  if (lane < 50) {
#pragma unroll
    for (int u = 0; u < 4; ++u) {
      sred[wv * 200 + f4 + u] = sa[u];
      qred[wv * 200 + f4 + u] = qa[u];
    }
  }
  __syncthreads();
  int tid = threadIdx.x;
  if (tid < 200) {
    double S = (sred[tid] + sred[200 + tid]) + (sred[400 + tid] + sred[600 + tid]);
    double Q = (qred[tid] + qred[200 + tid]) + (qred[400 + tid] + qred[600 + tid]);
    pstat[(long)blockIdx.x * 400 + tid] = S;
    pstat[(long)blockIdx.x * 400 + 200 + tid] = Q;
  }
}

// reduce nblk partials (layout [i][400]: sums at +f, sumsq at +200+f)
__global__ __launch_bounds__(256) void k_bn_fin(const double* __restrict__ part,
                                                int nblk,
                                                const float* __restrict__ g,
                                                const float* __restrict__ b,
                                                float* __restrict__ scale,
                                                float* __restrict__ shift) {
  int f = blockIdx.x;  // 0..199
  int tid = threadIdx.x;
  double S = 0.0, S2 = 0.0;
  for (int i = tid; i < nblk; i += 256) {
    S += part[(long)i * 400 + f];
    S2 += part[(long)i * 400 + 200 + f];
  }
  __shared__ double smS[256], smS2[256];
  smS[tid] = S; smS2[tid] = S2;
  __syncthreads();
  for (int off = 128; off > 0; off >>= 1) {
    if (tid < off) { smS[tid] += smS[tid + off]; smS2[tid] += smS2[tid + off]; }
    __syncthreads();
  }
  if (tid == 0) {
    double mean = smS[0] / N_ENT;
    double var = smS2[0] / N_ENT - mean * mean;
    double inv = 1.0 / sqrt(var + 1e-5);
    float sc = g[f] * (float)inv;
    scale[f] = sc;
    shift[f] = b[f] - (float)mean * sc;
  }
}

// reduce per-GEMM-block partials pstat[[GM][2][128][2]] -> scale/shift
__global__ __launch_bounds__(256) void k_bn_fin2(const double* __restrict__ pstat,
                                                 int nblk,
                                                 const float* __restrict__ g,
                                                 const float* __restrict__ b,
                                                 float* __restrict__ scale,
                                                 float* __restrict__ shift) {
  int f = blockIdx.x;  // 0..199
  int by = f >> 7, col = f & 127;
  int tid = threadIdx.x;
  double S = 0.0, S2 = 0.0;
  for (int bx = tid; bx < nblk; bx += 256) {
    long pb = (((long)bx * 2 + by) * 128 + col) * 2;
    S += pstat[pb];
    S2 += pstat[pb + 1];
  }
  __shared__ double smS[256], smS2[256];
  smS[tid] = S; smS2[tid] = S2;
  __syncthreads();
  for (int off = 128; off > 0; off >>= 1) {
    if (tid < off) { smS[tid] += smS[tid + off]; smS2[tid] += smS2[tid + off]; }
    __syncthreads();
  }
  if (tid == 0) {
    double mean = smS[0] / N_ENT;
    double var = smS2[0] / N_ENT - mean * mean;
    double inv = 1.0 / sqrt(var + 1e-5);
    float sc = g[f] * (float)inv;
    scale[f] = sc;
    shift[f] = b[f] - (float)mean * sc;
  }
}

// ---------------- merged split kernels ----------------

#define NS_BLK 2048
#define Q_BLK  ((B_ * KP_D + 255) / 256)   // 896
__global__ void k_split_all(const float* __restrict__ X,
                            const float* __restrict__ scale,
                            const float* __restrict__ shift,
                            const float* __restrict__ relE,
                            const int* __restrict__ subj,
                            const int* __restrict__ rel,
                            ushort_t* __restrict__ H, ushort_t* __restrict__ L,
                            ushort_t* __restrict__ QH, ushort_t* __restrict__ QL) {
  if (blockIdx.x < NS_BLK) {
    const long total = (long)N_ENT * (KP_D / 4);
    for (long i4 = (long)blockIdx.x * 256 + threadIdx.x; i4 < total;
         i4 += (long)NS_BLK * 256) {
      int r = (int)(i4 / (KP_D / 4));
      int c4 = (int)(i4 % (KP_D / 4)) * 4;
      float vv[4] = {0.f, 0.f, 0.f, 0.f};
      if (c4 < D_) {
        float4 v = *(const float4*)(X + (long)r * D_ + c4);
        vv[0] = fmaxf(fmaf(v.x, scale[c4 + 0], shift[c4 + 0]), 0.f);
        vv[1] = fmaxf(fmaf(v.y, scale[c4 + 1], shift[c4 + 1]), 0.f);
        vv[2] = fmaxf(fmaf(v.z, scale[c4 + 2], shift[c4 + 2]), 0.f);
        vv[3] = fmaxf(fmaf(v.w, scale[c4 + 3], shift[c4 + 3]), 0.f);
      }
      ushort_t h[4], l[4];
#pragma unroll
      for (int t = 0; t < 4; t++) {
        h[t] = f2bf(vv[t]);
        l[t] = f2bf(vv[t] - bf2f(h[t]));
      }
      long o = (long)r * KP_D + c4;
      *(uint2*)(H + o) = make_uint2((unsigned)h[0] | ((unsigned)h[1] << 16),
                                    (unsigned)h[2] | ((unsigned)h[3] << 16));
      *(uint2*)(L + o) = make_uint2((unsigned)l[0] | ((unsigned)l[1] << 16),
                                    (unsigned)l[2] | ((unsigned)l[3] << 16));
    }
  } else {
    int i = (blockIdx.x - NS_BLK) * 256 + threadIdx.x;
    if (i >= B_ * KP_D) return;
    int b = i / KP_D, kp = i - b * KP_D;
    float v = 0.f;
    if (kp < D_) {
      float e = X[(long)subj[b] * D_ + kp];
      e = fmaxf(fmaf(e, scale[kp], shift[kp]), 0.f);
      v = e * relE[(long)rel[b] * D_ + kp];
    }
    ushort_t h = f2bf(v);
    QH[i] = h;
    QL[i] = f2bf(v - bf2f(h));
  }
}

// ---------------- merged weight prep (5 jobs, block-range dispatch) ---------
__device__ __forceinline__ void tsplit_one(const float* __restrict__ W, int K,
                                           int Nc, int Kp, ushort_t* __restrict__ H,
                                           ushort_t* __restrict__ L, int i) {
  if (i >= Nc * Kp) return;
  int n = i / Kp, kp = i - n * Kp;
  float v = (kp < K) ? W[(long)kp * Nc + n] : 0.f;
  ushort_t h = f2bf(v);
  H[i] = h;
  L[i] = f2bf(v - bf2f(h));
}

__global__ void k_prep(const float* __restrict__ lin_w,
                       const float* __restrict__ concat_w,
                       const float* __restrict__ emb_e,
                       const float* __restrict__ w_rel,
                       ushort_t* __restrict__ linw_h, ushort_t* __restrict__ linw_l,
                       ushort_t* __restrict__ cw0_h, ushort_t* __restrict__ cw0_l,
                       ushort_t* __restrict__ cw1_h, ushort_t* __restrict__ cw1_l,
                       float* __restrict__ embeT, float* __restrict__ wrT) {
  int blk = blockIdx.x;
  int tid = threadIdx.x;
  if (blk < 100) {
    tsplit_one(lin_w, D0_, D_, KP_D0, linw_h, linw_l, blk * 256 + tid);
  } else if (blk < 275) {
    tsplit_one(concat_w, D_, D_, KP_D, cw0_h, cw0_l, (blk - 100) * 256 + tid);
  } else if (blk < 450) {
    tsplit_one(concat_w + D_ * D_, D_, D_, KP_D, cw1_h, cw1_l, (blk - 275) * 256 + tid);
  } else if (blk < 529) {
    int i = (blk - 450) * 256 + tid;
    if (i < D0_ * D_) { int r = i / D_, c = i - r * D_; embeT[c * D0_ + r] = emb_e[i]; }
  } else {
    int i = (blk - 529) * 256 + tid;
    if (i < D_ * D_) { int r = i / D_, c = i - r * D_; wrT[c * D_ + r] = w_rel[i]; }
  }
}

// ---------------- score GEMM (r17 config + VOLATILE q pin) ------------------
__global__ __launch_bounds__(256, 2) void k_score4(
    const ushort_t* __restrict__ Ah, const ushort_t* __restrict__ Al,
    const ushort_t* __restrict__ Bh, const ushort_t* __restrict__ Bl,
    float* __restrict__ C) {
  constexpr int KP = KP_D;  // 224, 7 K-steps
  __shared__ __align__(16) ushort_t lds[2 * 14336];
  const int tid = threadIdx.x;
  const int wave = tid >> 6, lane = tid & 63;
  const int l15 = lane & 15, l4 = lane >> 4;

  int g = (blockIdx.x & 7) * 1563 + (blockIdx.x >> 3);
  const int bm = (g & 7) * 128;       // q chunk (8 of 128)
  const int bn = (g >> 3) * 64;       // ent panel

  // ---- q loads, VOLATILE: may not be remat'd/duplicated -> truly resident --
  bf16x8 qh[2][7], ql[2][7];
#pragma unroll
  for (int i = 0; i < 2; ++i) {
    long rowa = (long)(bm + wave * 32 + i * 16 + l15) * KP + l4 * 8;
#pragma unroll
    for (int k = 0; k < 7; ++k) {
      qh[i][k] = *(volatile const bf16x8*)(Ah + rowa + k * 32);
      ql[i][k] = *(volatile const bf16x8*)(Al + rowa + k * 32);
    }
  }

  // ---- stage ent panel once (56 chunks x 1KB, swizzled slots) ----
#pragma unroll
  for (int jj = 0; jj < 14; ++jj) {
    int c = wave * 14 + jj;
    int u = c * 64 + lane;
    int isl = (u >= 1792) ? 1 : 0;
    int u2 = u - isl * 1792;
    int kst = u2 >> 8;
    int rem = u2 & 255;
    int r = rem >> 2;
    int slot = rem & 3;
    int srcslot = slot ^ ((r >> 1) & 3);
    int rowg = bn + r; if (rowg > N_ENT - 1) rowg = N_ENT - 1;
    const ushort_t* src = (isl ? Bl : Bh) + (long)rowg * KP + kst * 32 + srcslot * 8;
    gld16(src, lds + c * 512);
  }
  __syncthreads();

  f32x4 acc[2][4] = {};   // [iq][je]
#pragma unroll
  for (int k = 0; k < 7; ++k) {
    bf16x8 eh[4], el[4];
#pragma unroll
    for (int j = 0; j < 4; ++j) {
      int rB = j * 16 + l15;
      int slot = l4 ^ ((rB >> 1) & 3);
      int ad = k * 2048 + rB * 32 + slot * 8;
      eh[j] = *(const bf16x8*)(lds + ad);
      el[j] = *(const bf16x8*)(lds + 14336 + ad);
    }
    __builtin_amdgcn_s_setprio(1);
#pragma unroll
    for (int i = 0; i < 2; ++i)
#pragma unroll
      for (int j = 0; j < 4; ++j) {
        acc[i][j] = __builtin_amdgcn_mfma_f32_16x16x32_bf16(eh[j], qh[i][k], acc[i][j], 0, 0, 0);
        acc[i][j] = __builtin_amdgcn_mfma_f32_16x16x32_bf16(eh[j], ql[i][k], acc[i][j], 0, 0, 0);
        acc[i][j] = __builtin_amdgcn_mfma_f32_16x16x32_bf16(el[j], qh[i][k], acc[i][j], 0, 0, 0);
      }
    __builtin_amdgcn_s_setprio(0);
  }

#pragma unroll
  for (int i = 0; i < 2; ++i) {
    int m = bm + wave * 32 + i * 16 + l15;   // q row = D col = lane&15
#pragma unroll
    for (int j = 0; j < 4; ++j) {
      int nb = bn + j * 16 + l4 * 4;         // ent rows = D rows = l4*4+v
      if (nb < N_ENT) {
        float4 o = make_float4(acc[i][j][0], acc[i][j][1], acc[i][j][2], acc[i][j][3]);
        *(float4*)(C + (long)m * N_ENT + nb) = o;
      }
    }
  }
}

// ---------------- MFMA GEMM, f32 A, fused BN/split; optional fused colstats --
template <bool BN_A, bool HAS_BIAS, bool STATS>
__global__ __launch_bounds__(256, 2) void k_mfma_af32(
    const float* __restrict__ A, int lda, int K,
    const ushort_t* __restrict__ Bh, const ushort_t* __restrict__ Bl,
    float* __restrict__ C, int M, int Nc, int Kp, long ldc,
    const float* __restrict__ scale, const float* __restrict__ shift,
    const float* __restrict__ bias, double* __restrict__ pstat) {
  __shared__ __align__(16) ushort_t lds[2 * 16384];
  __shared__ float sc_lds[KP_D], sh_lds[KP_D];
  const int tid = threadIdx.x;
  const int wave = tid >> 6, lane = tid & 63;
  const int bm = blockIdx.x * 128, bn = blockIdx.y * 128;
  const int wr = (wave >> 1) * 64, wc = (wave & 1) * 64;
  const int l15 = lane & 15, l4 = lane >> 4;
  const int NT = Kp >> 5;

  if (BN_A) {
    for (int i = tid; i < Kp; i += 256) {
      sc_lds[i] = (i < K) ? scale[i] : 0.f;
      sh_lds[i] = (i < K) ? shift[i] : 0.f;
    }
    __syncthreads();
  }

  const int ar = tid >> 1;
  const int acb = (tid & 1) * 16;
  int arow = bm + ar; if (arow > M - 1) arow = M - 1;
  const int aswz = (ar >> 1) & 3;
  const int s0 = (((acb >> 3) + 0) ^ aswz) * 8;
  const int s1 = (((acb >> 3) + 1) ^ aswz) * 8;

  auto loadA = [&](int kt, float4* va) {
    int kc = kt * 32 + acb;
    const float* ap = A + (long)arow * lda + kc;
    if (kc + 16 <= K) {
#pragma unroll
      for (int q = 0; q < 4; q++) va[q] = *(const float4*)(ap + q * 4);
    } else {
#pragma unroll
      for (int q = 0; q < 4; q++) {
        float t0 = (kc + q * 4 + 0 < K) ? ap[q * 4 + 0] : 0.f;
        float t1 = (kc + q * 4 + 1 < K) ? ap[q * 4 + 1] : 0.f;
        float t2 = (kc + q * 4 + 2 < K) ? ap[q * 4 + 2] : 0.f;
        float t3 = (kc + q * 4 + 3 < K) ? ap[q * 4 + 3] : 0.f;
        va[q] = make_float4(t0, t1, t2, t3);
      }
    }
  };

  auto writeA = [&](int kt, int ph, float4* va) {
    float v[16];
#pragma unroll
    for (int q = 0; q < 4; q++) {
      v[q * 4 + 0] = va[q].x; v[q * 4 + 1] = va[q].y;
      v[q * 4 + 2] = va[q].z; v[q * 4 + 3] = va[q].w;
    }
    if (BN_A) {
      int kc = kt * 32 + acb;
#pragma unroll
      for (int e = 0; e < 16; e++) {
        int col = kc + e;
        if (col < K) v[e] = fmaxf(fmaf(v[e], sc_lds[col], sh_lds[col]), 0.f);
      }
    }
    unsigned hh[8], ll[8];
#pragma unroll
    for (int e = 0; e < 8; e++) {
      ushort_t h0 = f2bf(v[2 * e]), h1 = f2bf(v[2 * e + 1]);
      ushort_t l0 = f2bf(v[2 * e] - bf2f(h0)), l1 = f2bf(v[2 * e + 1] - bf2f(h1));
      hh[e] = (unsigned)h0 | ((unsigned)h1 << 16);
      ll[e] = (unsigned)l0 | ((unsigned)l1 << 16);
    }
    ushort_t* baseA = lds + ph * 16384 + ar * 32;
    *(uint4*)(baseA + s0) = make_uint4(hh[0], hh[1], hh[2], hh[3]);
    *(uint4*)(baseA + s1) = make_uint4(hh[4], hh[5], hh[6], hh[7]);
    ushort_t* baseL = baseA + 4096;
    *(uint4*)(baseL + s0) = make_uint4(ll[0], ll[1], ll[2], ll[3]);
    *(uint4*)(baseL + s1) = make_uint4(ll[4], ll[5], ll[6], ll[7]);
  };

  auto stageB = [&](int kt, int ph) {
#pragma unroll
    for (int j = 0; j < 4; ++j) {
      int c = 16 + wave * 4 + j;
      int buf = c >> 3;
      int r = (c & 7) * 16 + (lane >> 2);
      int sg = (lane & 3) ^ ((r >> 1) & 3);
      const ushort_t* bp = (buf == 2) ? Bh : Bl;
      int rowg = bn + r; if (rowg > Nc - 1) rowg = Nc - 1;
      gld16(bp + (long)rowg * Kp + kt * 32 + sg * 8, lds + ph * 16384 + c * 512);
    }
  };

  f32x4 acc[4][4] = {};
  {
    float4 va[4];
    loadA(0, va);
    writeA(0, 0, va);
    stageB(0, 0);
  }
  __syncthreads();
  int p = 0;
  for (int t = 0; t < NT; ++t) {
    float4 va[4];
    const bool pre = (t + 1 < NT);
    if (pre) {
      loadA(t + 1, va);
      stageB(t + 1, p ^ 1);
    }
    const ushort_t* base = lds + p * 16384;
    bf16x8 a_h[4], a_l[4], b_h[4], b_l[4];
#pragma unroll
    for (int i = 0; i < 4; i++) {
      int rA = wr + i * 16 + l15;
      int sA = (l4 ^ ((rA >> 1) & 3)) * 8;
      a_h[i] = *(const bf16x8*)(base + rA * 32 + sA);
      a_l[i] = *(const bf16x8*)(base + 4096 + rA * 32 + sA);
      int rB = wc + i * 16 + l15;
      int sB = (l4 ^ ((rB >> 1) & 3)) * 8;
      b_h[i] = *(const bf16x8*)(base + 8192 + rB * 32 + sB);
      b_l[i] = *(const bf16x8*)(base + 12288 + rB * 32 + sB);
    }
#pragma unroll
    for (int i = 0; i < 4; i++)
#pragma unroll
      for (int j = 0; j < 4; j++) {
        acc[i][j] = __builtin_amdgcn_mfma_f32_16x16x32_bf16(a_h[i], b_h[j], acc[i][j], 0, 0, 0);
        acc[i][j] = __builtin_amdgcn_mfma_f32_16x16x32_bf16(a_l[i], b_h[j], acc[i][j], 0, 0, 0);
        acc[i][j] = __builtin_amdgcn_mfma_f32_16x16x32_bf16(a_h[i], b_l[j], acc[i][j], 0, 0, 0);
      }
    if (pre) writeA(t + 1, p ^ 1, va);
    __syncthreads();
    p ^= 1;
  }

#pragma unroll
  for (int i = 0; i < 4; i++) {
    int mrow = bm + wr + i * 16 + l4 * 4;
#pragma unroll
    for (int j = 0; j < 4; j++) {
      int n = bn + wc + j * 16 + l15;
      if (n >= Nc) continue;
      float bb = HAS_BIAS ? bias[n] : 0.f;
#pragma unroll
      for (int v = 0; v < 4; v++) {
        int m = mrow + v;
        if (m < M) C[(long)m * ldc + n] = acc[i][j][v] + bb;
      }
    }
  }

  if (STATS) {
    double* sred = (double*)lds;           // [8][128]
    double* qred = ((double*)lds) + 1024;  // [8][128]
    const int slot = (wave >> 1) * 4 + l4; // 0..7
#pragma unroll
    for (int j = 0; j < 4; j++) {
      int colt = wc + j * 16 + l15;        // 0..127 within tile
      int n = bn + colt;
      double s = 0.0, q = 0.0;
      if (n < Nc) {
        float bb = HAS_BIAS ? bias[n] : 0.f;
#pragma unroll
        for (int i = 0; i < 4; i++) {
          int mrow = bm + wr + i * 16 + l4 * 4;
#pragma unroll
          for (int v = 0; v < 4; v++) {
            if (mrow + v < M) {
              float val = acc[i][j][v] + bb;
              s += val;
              q += (double)val * val;
            }
          }
        }
      }
      sred[slot * 128 + colt] = s;
      qred[slot * 128 + colt] = q;
    }
    __syncthreads();
    if (tid < 128) {
      double S = 0.0, Q = 0.0;
#pragma unroll
      for (int sl = 0; sl < 8; sl++) {
        S += sred[sl * 128 + tid];
        Q += qred[sl * 128 + tid];
      }
      long pb = (((long)blockIdx.x * 2 + blockIdx.y) * 128 + tid) * 2;
      pstat[pb] = S;
      pstat[pb + 1] = Q;
    }
  }
}

// ---------------- small f32 GEMM (tiny rel transforms) ----------------
template <int TM, int TN>
__global__ __launch_bounds__(256) void k_gemm_abt(
    const float* __restrict__ A, const float* __restrict__ Bm, float* __restrict__ C,
    int M, int Nc, int K, long ldc) {
  constexpr int BM = TM * 16, BN = TN * 16, KC = 20;
  __shared__ float As[BM * KC];
  __shared__ float Bs[BN * KC];
  const int tid = threadIdx.x;
  const int tx = tid & 15, ty = tid >> 4;
  const int bm = blockIdx.x * BM, bn = blockIdx.y * BN;
  float acc[TM][TN];
#pragma unroll
  for (int i = 0; i < TM; i++)
#pragma unroll
    for (int j = 0; j < TN; j++) acc[i][j] = 0.f;
  for (int kc = 0; kc < K; kc += KC) {
    for (int i4 = tid; i4 < BM * 5; i4 += 256) {
      int r = i4 / 5, kq = (i4 - r * 5) * 4;
      int row = bm + r; if (row > M - 1) row = M - 1;
      *(float4*)(As + r * KC + kq) = *(const float4*)(A + (long)row * K + kc + kq);
    }
    for (int i4 = tid; i4 < BN * 5; i4 += 256) {
      int r = i4 / 5, kq = (i4 - r * 5) * 4;
      int row = bn + r; if (row > Nc - 1) row = Nc - 1;
      *(float4*)(Bs + r * KC + kq) = *(const float4*)(Bm + (long)row * K + kc + kq);
    }
    __syncthreads();
#pragma unroll
    for (int k4 = 0; k4 < KC; k4 += 4) {
      float4 af[TM], bf[TN];
#pragma unroll
      for (int i = 0; i < TM; i++) af[i] = *(const float4*)(As + (i * 16 + ty) * KC + k4);
#pragma unroll
      for (int j = 0; j < TN; j++) bf[j] = *(const float4*)(Bs + (j * 16 + tx) * KC + k4);
#pragma unroll
      for (int i = 0; i < TM; i++)
#pragma unroll
        for (int j = 0; j < TN; j++) {
          acc[i][j] = fmaf(af[i].x, bf[j].x, acc[i][j]);
          acc[i][j] = fmaf(af[i].y, bf[j].y, acc[i][j]);
          acc[i][j] = fmaf(af[i].z, bf[j].z, acc[i][j]);
          acc[i][j] = fmaf(af[i].w, bf[j].w, acc[i][j]);
        }
    }
    __syncthreads();
  }
#pragma unroll
  for (int i = 0; i < TM; i++) {
    int m = bm + i * 16 + ty;
    if (m >= M) continue;
#pragma unroll
    for (int j = 0; j < TN; j++) {
      int n = bn + j * 16 + tx;
      if (n < Nc) C[(long)m * ldc + n] = acc[i][j];
    }
  }
}

// ---------------------------------------------------------------------------

extern "C" void kernel_launch(void* const* d_in, const int* in_sizes, int n_in,
                              void* d_out, int out_size, void* d_ws, size_t ws_size,
                              hipStream_t stream) {
  const int* src_id = (const int*)d_in[0];
  const int* dst_id = (const int*)d_in[1];
  const int* e_type = (const int*)d_in[2];
  const int* subj = (const int*)d_in[3];
  const int* rel = (const int*)d_in[4];
  const float* emb_h = (const float*)d_in[5];
  const float* emb_e = (const float*)d_in[6];
  const float* lin_w = (const float*)d_in[7];
  const float* lin_b = (const float*)d_in[8];
  const float* rel_wt = (const float*)d_in[9];
  const float* w_rel = (const float*)d_in[10];
  const float* agg_bn_g = (const float*)d_in[11];
  const float* agg_bn_b = (const float*)d_in[12];
  const float* cell_bn_g = (const float*)d_in[13];
  const float* cell_bn_b = (const float*)d_in[14];
  const float* concat_w = (const float*)d_in[15];
  const float* concat_b = (const float*)d_in[16];
  float* out = (float*)d_out;

  // ---- d_ws: only score-GEMM operands (read while d_out is written) ----
  char* w = (char*)d_ws;
  ushort_t* ent_h = (ushort_t*)(w + 0);           // 44,800,000
  ushort_t* ent_l = (ushort_t*)(w + 44800000);    // 44,800,000
  ushort_t* q_h   = (ushort_t*)(w + 89600000);    //    458,752
  ushort_t* q_l   = (ushort_t*)(w + 90112000);    //    458,752

  // ---- d_out front as temp (all dead before score GEMM) ----
  char* ob = (char*)d_out;
  float* ent    = (float*)(ob + 0);             // 80,000,000
  float* tmp    = (float*)(ob + 80000000);      // 80,000,000
  double* part  = (double*)(ob + 160000000);    //  6,553,600 (1563*400*8 = 5MB fits)
  int* counts   = (int*)(ob + 166600000);       //    400,000
  int* row_ptr  = (int*)(ob + 167000000);
  int* cursor   = (int*)(ob + 167400000);
  int* csr_src  = (int*)(ob + 167800000);       //  1,600,000
  int* csr_et   = (int*)(ob + 169400000);       //  1,600,000
  float* relA   = (float*)(ob + 171800000);     //    380,000
  float* relB   = (float*)(ob + 172180000);     //    380,000
  float* embeT  = (float*)(ob + 172560000);     //     80,000
  float* wrT    = (float*)(ob + 172640000);     //    160,000
  ushort_t* linw_h = (ushort_t*)(ob + 172800000);  // 51,200
  ushort_t* linw_l = (ushort_t*)(ob + 172851200);  // 51,200
  ushort_t* cw0_h  = (ushort_t*)(ob + 172902400);  // 89,600
  ushort_t* cw0_l  = (ushort_t*)(ob + 172992000);
  ushort_t* cw1_h  = (ushort_t*)(ob + 173081600);
  ushort_t* cw1_l  = (ushort_t*)(ob + 173171200);
  float* scaleb = (float*)(ob + 173260800);     // 1,024
  float* shiftb = (float*)(ob + 173261824);     // 1,024
  int* bsum     = (int*)(ob + 173262848);       //   512
  double* pstat = (double*)(ob + 173263360);    // 3,203,072 (782*2*128*2*8)

  // ---- CSR build (real edges only) ----
  (void)hipMemsetAsync(counts, 0, N_ENT * sizeof(int), stream);
  k_hist<<<(N_EDGE + 255) / 256, 256, 0, stream>>>(dst_id, counts);
  const int NB = (N_ENT + 1023) / 1024;  // 98
  k_scan_block<<<NB, 256, 0, stream>>>(counts, row_ptr, bsum);
  k_scan_tops<<<1, 256, 0, stream>>>(bsum, NB);
  k_scan_add<<<(N_ENT + 255) / 256, 256, 0, stream>>>(row_ptr, bsum, cursor);
  k_fill<<<(N_EDGE + 255) / 256, 256, 0, stream>>>(src_id, dst_id, e_type, cursor,
                                                   csr_src, csr_et);

  // ---- weight prep (merged: 3 tsplit + 2 transpose) ----
  k_prep<<<686, 256, 0, stream>>>(lin_w, concat_w, emb_e, w_rel,
                                  linw_h, linw_l, cw0_h, cw0_l, cw1_h, cw1_l,
                                  embeT, wrT);

  const int GM = (N_ENT + 127) / 128;  // 782
  const int GA = (N_ENT + 63) / 64;    // 1563 aggregate blocks (64 nodes each)

  // ---- init projections (A = emb_h f32, fused split in-kernel) ----
  k_mfma_af32<false, true, false><<<dim3(GM, 2), 256, 0, stream>>>(
      emb_h, D0_, D0_, linw_h, linw_l, ent, N_ENT, D_, KP_D0, (long)D_,
      nullptr, nullptr, lin_b, nullptr);
  k_gemm_abt<8, 4><<<dim3(4, 4), 256, 0, stream>>>(rel_wt, embeT, relA, NREL_, D_,
                                                   D0_, (long)D_);

  // ================= layer 0 =================
  k_aggregate<false><<<GA, 256, 0, stream>>>(ent, relA, row_ptr, counts,
                                             csr_src, csr_et, tmp, nullptr, nullptr,
                                             part);
  k_bn_fin<<<D_, 256, 0, stream>>>(part, GA, agg_bn_g, agg_bn_b, scaleb, shiftb);
  k_mfma_af32<true, true, true><<<dim3(GM, 2), 256, 0, stream>>>(
      tmp, D_, D_, cw0_h, cw0_l, ent, N_ENT, D_, KP_D, (long)D_,
      scaleb, shiftb, concat_b, pstat);
  k_bn_fin2<<<D_, 256, 0, stream>>>(pstat, GM, cell_bn_g, cell_bn_b, scaleb, shiftb);
  // cell-BN0 not materialized: fused into layer-1 aggregate's gather
  k_gemm_abt<8, 4><<<dim3(4, 4), 256, 0, stream>>>(relA, wrT, relB, NREL_, D_, D_,
                                                   (long)D_);

  // ================= layer 1 =================
  k_aggregate<true><<<GA, 256, 0, stream>>>(ent, relB, row_ptr, counts,
                                            csr_src, csr_et, tmp, scaleb, shiftb,
                                            part);
  k_bn_fin<<<D_, 256, 0, stream>>>(part, GA, agg_bn_g + D_, agg_bn_b + D_,
                                   scaleb, shiftb);
  k_mfma_af32<true, true, true><<<dim3(GM, 2), 256, 0, stream>>>(
      tmp, D_, D_, cw1_h, cw1_l, ent, N_ENT, D_, KP_D, (long)D_,
      scaleb, shiftb, concat_b + D_, pstat);
  k_bn_fin2<<<D_, 256, 0, stream>>>(pstat, GM, cell_bn_g + D_, cell_bn_b + D_,
                                    scaleb, shiftb);
  // rel transform for the scorer
  k_gemm_abt<8, 4><<<dim3(4, 4), 256, 0, stream>>>(relB, wrT, relA, NREL_, D_, D_,
                                                   (long)D_);
  // merged: ent hi/lo split (no f32 writeback) + BN-fused q split
  k_split_all<<<NS_BLK + Q_BLK, 256, 0, stream>>>(ent, scaleb, shiftb, relA,
                                                  subj, rel, ent_h, ent_l, q_h, q_l);

  // ---- DistMult score: r17 config + volatile q pin ----
  k_score4<<<dim3(8 * 1563), 256, 0, stream>>>(q_h, q_l, ent_h, ent_l, out);
}

// Round 22
// 956.239 us; speedup vs baseline: 1.0362x; 1.0362x over previous
//
#include <hip/hip_runtime.h>

// ---------------------------------------------------------------------------
// CompGCN-style network. MFMA split-bf16 (hi/lo, 3-term) GEMMs.
// Round 22: REVERT to the r20-passing config (959us, best measured).
// r21's volatile q-pin refuted (VGPR still 88, dur 256->294: volatile forces
// strict ordering/L1-bypass without achieving residency). Score chapter
// closed: plain+clobber/asm/SGB/volatile all fail; r17 config is the floor.
//   N=100000 ents, E=400000 edges, D=200, D0=100, NREL=475, B=1024, L=2
// ---------------------------------------------------------------------------

#define N_ENT  100000
#define N_EDGE 400000
#define D_     200
#define D0_    100
#define NREL_  475
#define B_     1024
#define KP_D   224   // D padded to multiple of 32
#define KP_D0  128   // D0 padded

typedef unsigned short ushort_t;
typedef __attribute__((ext_vector_type(8))) short bf16x8;
typedef __attribute__((ext_vector_type(4))) float f32x4;

__device__ __forceinline__ ushort_t f2bf(float x) {
  unsigned u = __float_as_uint(x);
  return (ushort_t)((u + 0x7FFFu + ((u >> 16) & 1u)) >> 16);
}
__device__ __forceinline__ float bf2f(ushort_t h) {
  return __uint_as_float(((unsigned)h) << 16);
}

__device__ __forceinline__ void gld16(const void* g, void* l) {
  __builtin_amdgcn_global_load_lds(
      (const __attribute__((address_space(1))) unsigned*)g,
      (__attribute__((address_space(3))) unsigned*)l, 16, 0, 0);
}

// ---------------- CSR build (real edges only; self-loops streamed) ----------

__global__ void k_hist(const int* __restrict__ dst_id, int* __restrict__ cnt) {
  int e = blockIdx.x * 256 + threadIdx.x;
  if (e < N_EDGE) atomicAdd(&cnt[dst_id[e]], 1);
}

__global__ __launch_bounds__(256) void k_scan_block(const int* __restrict__ cnt,
                                                    int* __restrict__ rp,
                                                    int* __restrict__ bsum) {
  __shared__ int sm[256];
  int tid = threadIdx.x;
  int base = blockIdx.x * 1024 + tid * 4;
  int v0 = (base + 0 < N_ENT) ? cnt[base + 0] : 0;
  int v1 = (base + 1 < N_ENT) ? cnt[base + 1] : 0;
  int v2 = (base + 2 < N_ENT) ? cnt[base + 2] : 0;
  int v3 = (base + 3 < N_ENT) ? cnt[base + 3] : 0;
  int tsum = v0 + v1 + v2 + v3;
  sm[tid] = tsum;
  __syncthreads();
  for (int off = 1; off < 256; off <<= 1) {
    int t = (tid >= off) ? sm[tid - off] : 0;
    __syncthreads();
    sm[tid] += t;
    __syncthreads();
  }
  int run = sm[tid] - tsum;
  if (base + 0 < N_ENT) { rp[base + 0] = run; } run += v0;
  if (base + 1 < N_ENT) { rp[base + 1] = run; } run += v1;
  if (base + 2 < N_ENT) { rp[base + 2] = run; } run += v2;
  if (base + 3 < N_ENT) { rp[base + 3] = run; }
  if (tid == 255) bsum[blockIdx.x] = sm[255];
}

__global__ void k_scan_tops(int* __restrict__ bsum, int nb) {
  __shared__ int sm[256];
  int tid = threadIdx.x;
  int v = (tid < nb) ? bsum[tid] : 0;
  sm[tid] = v;
  __syncthreads();
  for (int off = 1; off < 256; off <<= 1) {
    int t = (tid >= off) ? sm[tid - off] : 0;
    __syncthreads();
    sm[tid] += t;
    __syncthreads();
  }
  if (tid < nb) bsum[tid] = sm[tid] - v;
}

__global__ void k_scan_add(int* __restrict__ rp, const int* __restrict__ bsum,
                           int* __restrict__ cursor) {
  int i = blockIdx.x * 256 + threadIdx.x;
  if (i < N_ENT) {
    int r = rp[i] + bsum[i >> 10];
    rp[i] = r;
    cursor[i] = r;
  }
}

__global__ void k_fill(const int* __restrict__ src_id, const int* __restrict__ dst_id,
                       const int* __restrict__ e_type, int* __restrict__ cursor,
                       int* __restrict__ cs, int* __restrict__ ct) {
  int e = blockIdx.x * 256 + threadIdx.x;
  if (e < N_EDGE) {
    int pos = atomicAdd(&cursor[dst_id[e]], 1);
    cs[pos] = src_id[e];
    ct[pos] = e_type[e];
  }
}

// ---------------- aggregation (fused column stats) ----------------

// 64 nodes per block: wave wv handles nodes [blk*64+wv*16, +16) sequentially;
// lanes 0..49 cover 200 features as float4. Per-lane f64 (sum,sumsq) across
// its 16 nodes; deterministic 4-wave LDS reduce -> pstat[blk][400].
template <bool BN>
__global__ __launch_bounds__(256) void k_aggregate(const float* __restrict__ ent,
                                                   const float* __restrict__ relE,
                                                   const int* __restrict__ rp,
                                                   const int* __restrict__ cnt,
                                                   const int* __restrict__ cs,
                                                   const int* __restrict__ ct,
                                                   float* __restrict__ out,
                                                   const float* __restrict__ scale,
                                                   const float* __restrict__ shift,
                                                   double* __restrict__ pstat) {
  __shared__ double sred[4 * 200];
  __shared__ double qred[4 * 200];
  const int wv = threadIdx.x >> 6;
  const int lane = threadIdx.x & 63;
  const int f4 = lane * 4;
  double sa[4] = {0, 0, 0, 0}, qa[4] = {0, 0, 0, 0};

  if (lane < 50) {
    float sc[4] = {0, 0, 0, 0}, sh[4] = {0, 0, 0, 0};
    if (BN) {
      float4 s4 = *(const float4*)(scale + f4);
      float4 h4 = *(const float4*)(shift + f4);
      sc[0] = s4.x; sc[1] = s4.y; sc[2] = s4.z; sc[3] = s4.w;
      sh[0] = h4.x; sh[1] = h4.y; sh[2] = h4.z; sh[3] = h4.w;
    }
    float4 rself = *(const float4*)(relE + (long)(NREL_ - 1) * D_ + f4);
    float rs[4] = {rself.x, rself.y, rself.z, rself.w};

    for (int t = 0; t < 16; ++t) {
      int n = blockIdx.x * 64 + wv * 16 + t;
      if (n >= N_ENT) break;

      float ax[4], ay[4] = {0, 0, 0, 0}, az[4] = {0, 0, 0, 0}, aw[4] = {0, 0, 0, 0};
      {
        float4 e = *(const float4*)(ent + (long)n * D_ + f4);
        float ee[4] = {e.x, e.y, e.z, e.w};
#pragma unroll
        for (int u = 0; u < 4; ++u) {
          if (BN) ee[u] = fmaxf(fmaf(ee[u], sc[u], sh[u]), 0.f);
          ax[u] = ee[u] * rs[u];
        }
      }

      int s0 = rp[n], e0 = s0 + cnt[n];
      int idx = s0;
      for (; idx + 4 <= e0; idx += 4) {
        int sA = cs[idx + 0], tA = ct[idx + 0];
        int sB = cs[idx + 1], tB = ct[idx + 1];
        int sC = cs[idx + 2], tC = ct[idx + 2];
        int sD = cs[idx + 3], tD = ct[idx + 3];
        float4 eA = *(const float4*)(ent + (long)sA * D_ + f4);
        float4 eB = *(const float4*)(ent + (long)sB * D_ + f4);
        float4 eC = *(const float4*)(ent + (long)sC * D_ + f4);
        float4 eD = *(const float4*)(ent + (long)sD * D_ + f4);
        float4 rA = *(const float4*)(relE + (long)tA * D_ + f4);
        float4 rB = *(const float4*)(relE + (long)tB * D_ + f4);
        float4 rC = *(const float4*)(relE + (long)tC * D_ + f4);
        float4 rD = *(const float4*)(relE + (long)tD * D_ + f4);
        float ea[4] = {eA.x, eA.y, eA.z, eA.w}, ra[4] = {rA.x, rA.y, rA.z, rA.w};
        float eb[4] = {eB.x, eB.y, eB.z, eB.w}, rb[4] = {rB.x, rB.y, rB.z, rB.w};
        float ec[4] = {eC.x, eC.y, eC.z, eC.w}, rc[4] = {rC.x, rC.y, rC.z, rC.w};
        float ed[4] = {eD.x, eD.y, eD.z, eD.w}, rd[4] = {rD.x, rD.y, rD.z, rD.w};
#pragma unroll
        for (int u = 0; u < 4; ++u) {
          if (BN) {
            ea[u] = fmaxf(fmaf(ea[u], sc[u], sh[u]), 0.f);
            eb[u] = fmaxf(fmaf(eb[u], sc[u], sh[u]), 0.f);
            ec[u] = fmaxf(fmaf(ec[u], sc[u], sh[u]), 0.f);
            ed[u] = fmaxf(fmaf(ed[u], sc[u], sh[u]), 0.f);
          }
          ax[u] = fmaf(ea[u], ra[u], ax[u]);
          ay[u] = fmaf(eb[u], rb[u], ay[u]);
          az[u] = fmaf(ec[u], rc[u], az[u]);
          aw[u] = fmaf(ed[u], rd[u], aw[u]);
        }
      }
      for (; idx < e0; ++idx) {
        int sA = cs[idx], tA = ct[idx];
        float4 eA = *(const float4*)(ent + (long)sA * D_ + f4);
        float4 rA = *(const float4*)(relE + (long)tA * D_ + f4);
        float ea[4] = {eA.x, eA.y, eA.z, eA.w}, ra[4] = {rA.x, rA.y, rA.z, rA.w};
#pragma unroll
        for (int u = 0; u < 4; ++u) {
          if (BN) ea[u] = fmaxf(fmaf(ea[u], sc[u], sh[u]), 0.f);
          ax[u] = fmaf(ea[u], ra[u], ax[u]);
        }
      }
      float o[4];
#pragma unroll
      for (int u = 0; u < 4; ++u) {
        o[u] = (ax[u] + ay[u]) + (az[u] + aw[u]);
        sa[u] += o[u];
        qa[u] += (double)o[u] * o[u];
      }
      *(float4*)(out + (long)n * D_ + f4) = make_float4(o[0], o[1], o[2], o[3]);
    }
  }

  if (lane < 50) {
#pragma unroll
    for (int u = 0; u < 4; ++u) {
      sred[wv * 200 + f4 + u] = sa[u];
      qred[wv * 200 + f4 + u] = qa[u];
    }
  }
  __syncthreads();
  int tid = threadIdx.x;
  if (tid < 200) {
    double S = (sred[tid] + sred[200 + tid]) + (sred[400 + tid] + sred[600 + tid]);
    double Q = (qred[tid] + qred[200 + tid]) + (qred[400 + tid] + qred[600 + tid]);
    pstat[(long)blockIdx.x * 400 + tid] = S;
    pstat[(long)blockIdx.x * 400 + 200 + tid] = Q;
  }
}

// reduce nblk partials (layout [i][400]: sums at +f, sumsq at +200+f)
__global__ __launch_bounds__(256) void k_bn_fin(const double* __restrict__ part,
                                                int nblk,
                                                const float* __restrict__ g,
                                                const float* __restrict__ b,
                                                float* __restrict__ scale,
                                                float* __restrict__ shift) {
  int f = blockIdx.x;  // 0..199
  int tid = threadIdx.x;
  double S = 0.0, S2 = 0.0;
  for (int i = tid; i < nblk; i += 256) {
    S += part[(long)i * 400 + f];
    S2 += part[(long)i * 400 + 200 + f];
  }
  __shared__ double smS[256], smS2[256];
  smS[tid] = S; smS2[tid] = S2;
  __syncthreads();
  for (int off = 128; off > 0; off >>= 1) {
    if (tid < off) { smS[tid] += smS[tid + off]; smS2[tid] += smS2[tid + off]; }
    __syncthreads();
  }
  if (tid == 0) {
    double mean = smS[0] / N_ENT;
    double var = smS2[0] / N_ENT - mean * mean;
    double inv = 1.0 / sqrt(var + 1e-5);
    float sc = g[f] * (float)inv;
    scale[f] = sc;
    shift[f] = b[f] - (float)mean * sc;
  }
}

// reduce per-GEMM-block partials pstat[[GM][2][128][2]] -> scale/shift
__global__ __launch_bounds__(256) void k_bn_fin2(const double* __restrict__ pstat,
                                                 int nblk,
                                                 const float* __restrict__ g,
                                                 const float* __restrict__ b,
                                                 float* __restrict__ scale,
                                                 float* __restrict__ shift) {
  int f = blockIdx.x;  // 0..199
  int by = f >> 7, col = f & 127;
  int tid = threadIdx.x;
  double S = 0.0, S2 = 0.0;
  for (int bx = tid; bx < nblk; bx += 256) {
    long pb = (((long)bx * 2 + by) * 128 + col) * 2;
    S += pstat[pb];
    S2 += pstat[pb + 1];
  }
  __shared__ double smS[256], smS2[256];
  smS[tid] = S; smS2[tid] = S2;
  __syncthreads();
  for (int off = 128; off > 0; off >>= 1) {
    if (tid < off) { smS[tid] += smS[tid + off]; smS2[tid] += smS2[tid + off]; }
    __syncthreads();
  }
  if (tid == 0) {
    double mean = smS[0] / N_ENT;
    double var = smS2[0] / N_ENT - mean * mean;
    double inv = 1.0 / sqrt(var + 1e-5);
    float sc = g[f] * (float)inv;
    scale[f] = sc;
    shift[f] = b[f] - (float)mean * sc;
  }
}

// ---------------- merged split kernels ----------------

#define NS_BLK 2048
#define Q_BLK  ((B_ * KP_D + 255) / 256)   // 896
__global__ void k_split_all(const float* __restrict__ X,
                            const float* __restrict__ scale,
                            const float* __restrict__ shift,
                            const float* __restrict__ relE,
                            const int* __restrict__ subj,
                            const int* __restrict__ rel,
                            ushort_t* __restrict__ H, ushort_t* __restrict__ L,
                            ushort_t* __restrict__ QH, ushort_t* __restrict__ QL) {
  if (blockIdx.x < NS_BLK) {
    const long total = (long)N_ENT * (KP_D / 4);
    for (long i4 = (long)blockIdx.x * 256 + threadIdx.x; i4 < total;
         i4 += (long)NS_BLK * 256) {
      int r = (int)(i4 / (KP_D / 4));
      int c4 = (int)(i4 % (KP_D / 4)) * 4;
      float vv[4] = {0.f, 0.f, 0.f, 0.f};
      if (c4 < D_) {
        float4 v = *(const float4*)(X + (long)r * D_ + c4);
        vv[0] = fmaxf(fmaf(v.x, scale[c4 + 0], shift[c4 + 0]), 0.f);
        vv[1] = fmaxf(fmaf(v.y, scale[c4 + 1], shift[c4 + 1]), 0.f);
        vv[2] = fmaxf(fmaf(v.z, scale[c4 + 2], shift[c4 + 2]), 0.f);
        vv[3] = fmaxf(fmaf(v.w, scale[c4 + 3], shift[c4 + 3]), 0.f);
      }
      ushort_t h[4], l[4];
#pragma unroll
      for (int t = 0; t < 4; t++) {
        h[t] = f2bf(vv[t]);
        l[t] = f2bf(vv[t] - bf2f(h[t]));
      }
      long o = (long)r * KP_D + c4;
      *(uint2*)(H + o) = make_uint2((unsigned)h[0] | ((unsigned)h[1] << 16),
                                    (unsigned)h[2] | ((unsigned)h[3] << 16));
      *(uint2*)(L + o) = make_uint2((unsigned)l[0] | ((unsigned)l[1] << 16),
                                    (unsigned)l[2] | ((unsigned)l[3] << 16));
    }
  } else {
    int i = (blockIdx.x - NS_BLK) * 256 + threadIdx.x;
    if (i >= B_ * KP_D) return;
    int b = i / KP_D, kp = i - b * KP_D;
    float v = 0.f;
    if (kp < D_) {
      float e = X[(long)subj[b] * D_ + kp];
      e = fmaxf(fmaf(e, scale[kp], shift[kp]), 0.f);
      v = e * relE[(long)rel[b] * D_ + kp];
    }
    ushort_t h = f2bf(v);
    QH[i] = h;
    QL[i] = f2bf(v - bf2f(h));
  }
}

// ---------------- merged weight prep (5 jobs, block-range dispatch) ---------
__device__ __forceinline__ void tsplit_one(const float* __restrict__ W, int K,
                                           int Nc, int Kp, ushort_t* __restrict__ H,
                                           ushort_t* __restrict__ L, int i) {
  if (i >= Nc * Kp) return;
  int n = i / Kp, kp = i - n * Kp;
  float v = (kp < K) ? W[(long)kp * Nc + n] : 0.f;
  ushort_t h = f2bf(v);
  H[i] = h;
  L[i] = f2bf(v - bf2f(h));
}

__global__ void k_prep(const float* __restrict__ lin_w,
                       const float* __restrict__ concat_w,
                       const float* __restrict__ emb_e,
                       const float* __restrict__ w_rel,
                       ushort_t* __restrict__ linw_h, ushort_t* __restrict__ linw_l,
                       ushort_t* __restrict__ cw0_h, ushort_t* __restrict__ cw0_l,
                       ushort_t* __restrict__ cw1_h, ushort_t* __restrict__ cw1_l,
                       float* __restrict__ embeT, float* __restrict__ wrT) {
  int blk = blockIdx.x;
  int tid = threadIdx.x;
  if (blk < 100) {
    tsplit_one(lin_w, D0_, D_, KP_D0, linw_h, linw_l, blk * 256 + tid);
  } else if (blk < 275) {
    tsplit_one(concat_w, D_, D_, KP_D, cw0_h, cw0_l, (blk - 100) * 256 + tid);
  } else if (blk < 450) {
    tsplit_one(concat_w + D_ * D_, D_, D_, KP_D, cw1_h, cw1_l, (blk - 275) * 256 + tid);
  } else if (blk < 529) {
    int i = (blk - 450) * 256 + tid;
    if (i < D0_ * D_) { int r = i / D_, c = i - r * D_; embeT[c * D0_ + r] = emb_e[i]; }
  } else {
    int i = (blk - 529) * 256 + tid;
    if (i < D_ * D_) { int r = i / D_, c = i - r * D_; wrT[c * D_ + r] = w_rel[i]; }
  }
}

// ---------------- score GEMM (r17 config: r10 + setprio, 255us, frozen) -----
__global__ __launch_bounds__(256, 2) void k_score4(
    const ushort_t* __restrict__ Ah, const ushort_t* __restrict__ Al,
    const ushort_t* __restrict__ Bh, const ushort_t* __restrict__ Bl,
    float* __restrict__ C) {
  constexpr int KP = KP_D;  // 224, 7 K-steps
  __shared__ __align__(16) ushort_t lds[2 * 14336];
  const int tid = threadIdx.x;
  const int wave = tid >> 6, lane = tid & 63;
  const int l15 = lane & 15, l4 = lane >> 4;

  int g = (blockIdx.x & 7) * 1563 + (blockIdx.x >> 3);
  const int bm = (g & 7) * 128;       // q chunk (8 of 128)
  const int bn = (g >> 3) * 64;       // ent panel

  bf16x8 qh[2][7], ql[2][7];
#pragma unroll
  for (int i = 0; i < 2; ++i) {
    long rowa = (long)(bm + wave * 32 + i * 16 + l15) * KP + l4 * 8;
#pragma unroll
    for (int k = 0; k < 7; ++k) {
      qh[i][k] = *(const bf16x8*)(Ah + rowa + k * 32);
      ql[i][k] = *(const bf16x8*)(Al + rowa + k * 32);
    }
  }

#pragma unroll
  for (int jj = 0; jj < 14; ++jj) {
    int c = wave * 14 + jj;
    int u = c * 64 + lane;
    int isl = (u >= 1792) ? 1 : 0;
    int u2 = u - isl * 1792;
    int kst = u2 >> 8;
    int rem = u2 & 255;
    int r = rem >> 2;
    int slot = rem & 3;
    int srcslot = slot ^ ((r >> 1) & 3);
    int rowg = bn + r; if (rowg > N_ENT - 1) rowg = N_ENT - 1;
    const ushort_t* src = (isl ? Bl : Bh) + (long)rowg * KP + kst * 32 + srcslot * 8;
    gld16(src, lds + c * 512);
  }
  __syncthreads();

  f32x4 acc[2][4] = {};   // [iq][je]
#pragma unroll
  for (int k = 0; k < 7; ++k) {
    bf16x8 eh[4], el[4];
#pragma unroll
    for (int j = 0; j < 4; ++j) {
      int rB = j * 16 + l15;
      int slot = l4 ^ ((rB >> 1) & 3);
      int ad = k * 2048 + rB * 32 + slot * 8;
      eh[j] = *(const bf16x8*)(lds + ad);
      el[j] = *(const bf16x8*)(lds + 14336 + ad);
    }
    __builtin_amdgcn_s_setprio(1);
#pragma unroll
    for (int i = 0; i < 2; ++i)
#pragma unroll
      for (int j = 0; j < 4; ++j) {
        acc[i][j] = __builtin_amdgcn_mfma_f32_16x16x32_bf16(eh[j], qh[i][k], acc[i][j], 0, 0, 0);
        acc[i][j] = __builtin_amdgcn_mfma_f32_16x16x32_bf16(eh[j], ql[i][k], acc[i][j], 0, 0, 0);
        acc[i][j] = __builtin_amdgcn_mfma_f32_16x16x32_bf16(el[j], qh[i][k], acc[i][j], 0, 0, 0);
      }
    __builtin_amdgcn_s_setprio(0);
  }

#pragma unroll
  for (int i = 0; i < 2; ++i) {
    int m = bm + wave * 32 + i * 16 + l15;   // q row = D col = lane&15
#pragma unroll
    for (int j = 0; j < 4; ++j) {
      int nb = bn + j * 16 + l4 * 4;         // ent rows = D rows = l4*4+v
      if (nb < N_ENT) {
        float4 o = make_float4(acc[i][j][0], acc[i][j][1], acc[i][j][2], acc[i][j][3]);
        *(float4*)(C + (long)m * N_ENT + nb) = o;
      }
    }
  }
}

// ---------------- MFMA GEMM, f32 A, fused BN/split; optional fused colstats --
template <bool BN_A, bool HAS_BIAS, bool STATS>
__global__ __launch_bounds__(256, 2) void k_mfma_af32(
    const float* __restrict__ A, int lda, int K,
    const ushort_t* __restrict__ Bh, const ushort_t* __restrict__ Bl,
    float* __restrict__ C, int M, int Nc, int Kp, long ldc,
    const float* __restrict__ scale, const float* __restrict__ shift,
    const float* __restrict__ bias, double* __restrict__ pstat) {
  __shared__ __align__(16) ushort_t lds[2 * 16384];
  __shared__ float sc_lds[KP_D], sh_lds[KP_D];
  const int tid = threadIdx.x;
  const int wave = tid >> 6, lane = tid & 63;
  const int bm = blockIdx.x * 128, bn = blockIdx.y * 128;
  const int wr = (wave >> 1) * 64, wc = (wave & 1) * 64;
  const int l15 = lane & 15, l4 = lane >> 4;
  const int NT = Kp >> 5;

  if (BN_A) {
    for (int i = tid; i < Kp; i += 256) {
      sc_lds[i] = (i < K) ? scale[i] : 0.f;
      sh_lds[i] = (i < K) ? shift[i] : 0.f;
    }
    __syncthreads();
  }

  const int ar = tid >> 1;
  const int acb = (tid & 1) * 16;
  int arow = bm + ar; if (arow > M - 1) arow = M - 1;
  const int aswz = (ar >> 1) & 3;
  const int s0 = (((acb >> 3) + 0) ^ aswz) * 8;
  const int s1 = (((acb >> 3) + 1) ^ aswz) * 8;

  auto loadA = [&](int kt, float4* va) {
    int kc = kt * 32 + acb;
    const float* ap = A + (long)arow * lda + kc;
    if (kc + 16 <= K) {
#pragma unroll
      for (int q = 0; q < 4; q++) va[q] = *(const float4*)(ap + q * 4);
    } else {
#pragma unroll
      for (int q = 0; q < 4; q++) {
        float t0 = (kc + q * 4 + 0 < K) ? ap[q * 4 + 0] : 0.f;
        float t1 = (kc + q * 4 + 1 < K) ? ap[q * 4 + 1] : 0.f;
        float t2 = (kc + q * 4 + 2 < K) ? ap[q * 4 + 2] : 0.f;
        float t3 = (kc + q * 4 + 3 < K) ? ap[q * 4 + 3] : 0.f;
        va[q] = make_float4(t0, t1, t2, t3);
      }
    }
  };

  auto writeA = [&](int kt, int ph, float4* va) {
    float v[16];
#pragma unroll
    for (int q = 0; q < 4; q++) {
      v[q * 4 + 0] = va[q].x; v[q * 4 + 1] = va[q].y;
      v[q * 4 + 2] = va[q].z; v[q * 4 + 3] = va[q].w;
    }
    if (BN_A) {
      int kc = kt * 32 + acb;
#pragma unroll
      for (int e = 0; e < 16; e++) {
        int col = kc + e;
        if (col < K) v[e] = fmaxf(fmaf(v[e], sc_lds[col], sh_lds[col]), 0.f);
      }
    }
    unsigned hh[8], ll[8];
#pragma unroll
    for (int e = 0; e < 8; e++) {
      ushort_t h0 = f2bf(v[2 * e]), h1 = f2bf(v[2 * e + 1]);
      ushort_t l0 = f2bf(v[2 * e] - bf2f(h0)), l1 = f2bf(v[2 * e + 1] - bf2f(h1));
      hh[e] = (unsigned)h0 | ((unsigned)h1 << 16);
      ll[e] = (unsigned)l0 | ((unsigned)l1 << 16);
    }
    ushort_t* baseA = lds + ph * 16384 + ar * 32;
    *(uint4*)(baseA + s0) = make_uint4(hh[0], hh[1], hh[2], hh[3]);
    *(uint4*)(baseA + s1) = make_uint4(hh[4], hh[5], hh[6], hh[7]);
    ushort_t* baseL = baseA + 4096;
    *(uint4*)(baseL + s0) = make_uint4(ll[0], ll[1], ll[2], ll[3]);
    *(uint4*)(baseL + s1) = make_uint4(ll[4], ll[5], ll[6], ll[7]);
  };

  auto stageB = [&](int kt, int ph) {
#pragma unroll
    for (int j = 0; j < 4; ++j) {
      int c = 16 + wave * 4 + j;
      int buf = c >> 3;
      int r = (c & 7) * 16 + (lane >> 2);
      int sg = (lane & 3) ^ ((r >> 1) & 3);
      const ushort_t* bp = (buf == 2) ? Bh : Bl;
      int rowg = bn + r; if (rowg > Nc - 1) rowg = Nc - 1;
      gld16(bp + (long)rowg * Kp + kt * 32 + sg * 8, lds + ph * 16384 + c * 512);
    }
  };

  f32x4 acc[4][4] = {};
  {
    float4 va[4];
    loadA(0, va);
    writeA(0, 0, va);
    stageB(0, 0);
  }
  __syncthreads();
  int p = 0;
  for (int t = 0; t < NT; ++t) {
    float4 va[4];
    const bool pre = (t + 1 < NT);
    if (pre) {
      loadA(t + 1, va);
      stageB(t + 1, p ^ 1);
    }
    const ushort_t* base = lds + p * 16384;
    bf16x8 a_h[4], a_l[4], b_h[4], b_l[4];
#pragma unroll
    for (int i = 0; i < 4; i++) {
      int rA = wr + i * 16 + l15;
      int sA = (l4 ^ ((rA >> 1) & 3)) * 8;
      a_h[i] = *(const bf16x8*)(base + rA * 32 + sA);
      a_l[i] = *(const bf16x8*)(base + 4096 + rA * 32 + sA);
      int rB = wc + i * 16 + l15;
      int sB = (l4 ^ ((rB >> 1) & 3)) * 8;
      b_h[i] = *(const bf16x8*)(base + 8192 + rB * 32 + sB);
      b_l[i] = *(const bf16x8*)(base + 12288 + rB * 32 + sB);
    }
#pragma unroll
    for (int i = 0; i < 4; i++)
#pragma unroll
      for (int j = 0; j < 4; j++) {
        acc[i][j] = __builtin_amdgcn_mfma_f32_16x16x32_bf16(a_h[i], b_h[j], acc[i][j], 0, 0, 0);
        acc[i][j] = __builtin_amdgcn_mfma_f32_16x16x32_bf16(a_l[i], b_h[j], acc[i][j], 0, 0, 0);
        acc[i][j] = __builtin_amdgcn_mfma_f32_16x16x32_bf16(a_h[i], b_l[j], acc[i][j], 0, 0, 0);
      }
    if (pre) writeA(t + 1, p ^ 1, va);
    __syncthreads();
    p ^= 1;
  }

#pragma unroll
  for (int i = 0; i < 4; i++) {
    int mrow = bm + wr + i * 16 + l4 * 4;
#pragma unroll
    for (int j = 0; j < 4; j++) {
      int n = bn + wc + j * 16 + l15;
      if (n >= Nc) continue;
      float bb = HAS_BIAS ? bias[n] : 0.f;
#pragma unroll
      for (int v = 0; v < 4; v++) {
        int m = mrow + v;
        if (m < M) C[(long)m * ldc + n] = acc[i][j][v] + bb;
      }
    }
  }

  if (STATS) {
    double* sred = (double*)lds;           // [8][128]
    double* qred = ((double*)lds) + 1024;  // [8][128]
    const int slot = (wave >> 1) * 4 + l4; // 0..7
#pragma unroll
    for (int j = 0; j < 4; j++) {
      int colt = wc + j * 16 + l15;        // 0..127 within tile
      int n = bn + colt;
      double s = 0.0, q = 0.0;
      if (n < Nc) {
        float bb = HAS_BIAS ? bias[n] : 0.f;
#pragma unroll
        for (int i = 0; i < 4; i++) {
          int mrow = bm + wr + i * 16 + l4 * 4;
#pragma unroll
          for (int v = 0; v < 4; v++) {
            if (mrow + v < M) {
              float val = acc[i][j][v] + bb;
              s += val;
              q += (double)val * val;
            }
          }
        }
      }
      sred[slot * 128 + colt] = s;
      qred[slot * 128 + colt] = q;
    }
    __syncthreads();
    if (tid < 128) {
      double S = 0.0, Q = 0.0;
#pragma unroll
      for (int sl = 0; sl < 8; sl++) {
        S += sred[sl * 128 + tid];
        Q += qred[sl * 128 + tid];
      }
      long pb = (((long)blockIdx.x * 2 + blockIdx.y) * 128 + tid) * 2;
      pstat[pb] = S;
      pstat[pb + 1] = Q;
    }
  }
}

// ---------------- small f32 GEMM (tiny rel transforms) ----------------
template <int TM, int TN>
__global__ __launch_bounds__(256) void k_gemm_abt(
    const float* __restrict__ A, const float* __restrict__ Bm, float* __restrict__ C,
    int M, int Nc, int K, long ldc) {
  constexpr int BM = TM * 16, BN = TN * 16, KC = 20;
  __shared__ float As[BM * KC];
  __shared__ float Bs[BN * KC];
  const int tid = threadIdx.x;
  const int tx = tid & 15, ty = tid >> 4;
  const int bm = blockIdx.x * BM, bn = blockIdx.y * BN;
  float acc[TM][TN];
#pragma unroll
  for (int i = 0; i < TM; i++)
#pragma unroll
    for (int j = 0; j < TN; j++) acc[i][j] = 0.f;
  for (int kc = 0; kc < K; kc += KC) {
    for (int i4 = tid; i4 < BM * 5; i4 += 256) {
      int r = i4 / 5, kq = (i4 - r * 5) * 4;
      int row = bm + r; if (row > M - 1) row = M - 1;
      *(float4*)(As + r * KC + kq) = *(const float4*)(A + (long)row * K + kc + kq);
    }
    for (int i4 = tid; i4 < BN * 5; i4 += 256) {
      int r = i4 / 5, kq = (i4 - r * 5) * 4;
      int row = bn + r; if (row > Nc - 1) row = Nc - 1;
      *(float4*)(Bs + r * KC + kq) = *(const float4*)(Bm + (long)row * K + kc + kq);
    }
    __syncthreads();
#pragma unroll
    for (int k4 = 0; k4 < KC; k4 += 4) {
      float4 af[TM], bf[TN];
#pragma unroll
      for (int i = 0; i < TM; i++) af[i] = *(const float4*)(As + (i * 16 + ty) * KC + k4);
#pragma unroll
      for (int j = 0; j < TN; j++) bf[j] = *(const float4*)(Bs + (j * 16 + tx) * KC + k4);
#pragma unroll
      for (int i = 0; i < TM; i++)
#pragma unroll
        for (int j = 0; j < TN; j++) {
          acc[i][j] = fmaf(af[i].x, bf[j].x, acc[i][j]);
          acc[i][j] = fmaf(af[i].y, bf[j].y, acc[i][j]);
          acc[i][j] = fmaf(af[i].z, bf[j].z, acc[i][j]);
          acc[i][j] = fmaf(af[i].w, bf[j].w, acc[i][j]);
        }
    }
    __syncthreads();
  }
#pragma unroll
  for (int i = 0; i < TM; i++) {
    int m = bm + i * 16 + ty;
    if (m >= M) continue;
#pragma unroll
    for (int j = 0; j < TN; j++) {
      int n = bn + j * 16 + tx;
      if (n < Nc) C[(long)m * ldc + n] = acc[i][j];
    }
  }
}

// ---------------------------------------------------------------------------

extern "C" void kernel_launch(void* const* d_in, const int* in_sizes, int n_in,
                              void* d_out, int out_size, void* d_ws, size_t ws_size,
                              hipStream_t stream) {
  const int* src_id = (const int*)d_in[0];
  const int* dst_id = (const int*)d_in[1];
  const int* e_type = (const int*)d_in[2];
  const int* subj = (const int*)d_in[3];
  const int* rel = (const int*)d_in[4];
  const float* emb_h = (const float*)d_in[5];
  const float* emb_e = (const float*)d_in[6];
  const float* lin_w = (const float*)d_in[7];
  const float* lin_b = (const float*)d_in[8];
  const float* rel_wt = (const float*)d_in[9];
  const float* w_rel = (const float*)d_in[10];
  const float* agg_bn_g = (const float*)d_in[11];
  const float* agg_bn_b = (const float*)d_in[12];
  const float* cell_bn_g = (const float*)d_in[13];
  const float* cell_bn_b = (const float*)d_in[14];
  const float* concat_w = (const float*)d_in[15];
  const float* concat_b = (const float*)d_in[16];
  float* out = (float*)d_out;

  // ---- d_ws: only score-GEMM operands (read while d_out is written) ----
  char* w = (char*)d_ws;
  ushort_t* ent_h = (ushort_t*)(w + 0);           // 44,800,000
  ushort_t* ent_l = (ushort_t*)(w + 44800000);    // 44,800,000
  ushort_t* q_h   = (ushort_t*)(w + 89600000);    //    458,752
  ushort_t* q_l   = (ushort_t*)(w + 90112000);    //    458,752

  // ---- d_out front as temp (all dead before score GEMM) ----
  char* ob = (char*)d_out;
  float* ent    = (float*)(ob + 0);             // 80,000,000
  float* tmp    = (float*)(ob + 80000000);      // 80,000,000
  double* part  = (double*)(ob + 160000000);    //  6,553,600 (1563*400*8 = 5MB fits)
  int* counts   = (int*)(ob + 166600000);       //    400,000
  int* row_ptr  = (int*)(ob + 167000000);
  int* cursor   = (int*)(ob + 167400000);
  int* csr_src  = (int*)(ob + 167800000);       //  1,600,000
  int* csr_et   = (int*)(ob + 169400000);       //  1,600,000
  float* relA   = (float*)(ob + 171800000);     //    380,000
  float* relB   = (float*)(ob + 172180000);     //    380,000
  float* embeT  = (float*)(ob + 172560000);     //     80,000
  float* wrT    = (float*)(ob + 172640000);     //    160,000
  ushort_t* linw_h = (ushort_t*)(ob + 172800000);  // 51,200
  ushort_t* linw_l = (ushort_t*)(ob + 172851200);  // 51,200
  ushort_t* cw0_h  = (ushort_t*)(ob + 172902400);  // 89,600
  ushort_t* cw0_l  = (ushort_t*)(ob + 172992000);
  ushort_t* cw1_h  = (ushort_t*)(ob + 173081600);
  ushort_t* cw1_l  = (ushort_t*)(ob + 173171200);
  float* scaleb = (float*)(ob + 173260800);     // 1,024
  float* shiftb = (float*)(ob + 173261824);     // 1,024
  int* bsum     = (int*)(ob + 173262848);       //   512
  double* pstat = (double*)(ob + 173263360);    // 3,203,072 (782*2*128*2*8)

  // ---- CSR build (real edges only) ----
  (void)hipMemsetAsync(counts, 0, N_ENT * sizeof(int), stream);
  k_hist<<<(N_EDGE + 255) / 256, 256, 0, stream>>>(dst_id, counts);
  const int NB = (N_ENT + 1023) / 1024;  // 98
  k_scan_block<<<NB, 256, 0, stream>>>(counts, row_ptr, bsum);
  k_scan_tops<<<1, 256, 0, stream>>>(bsum, NB);
  k_scan_add<<<(N_ENT + 255) / 256, 256, 0, stream>>>(row_ptr, bsum, cursor);
  k_fill<<<(N_EDGE + 255) / 256, 256, 0, stream>>>(src_id, dst_id, e_type, cursor,
                                                   csr_src, csr_et);

  // ---- weight prep (merged: 3 tsplit + 2 transpose) ----
  k_prep<<<686, 256, 0, stream>>>(lin_w, concat_w, emb_e, w_rel,
                                  linw_h, linw_l, cw0_h, cw0_l, cw1_h, cw1_l,
                                  embeT, wrT);

  const int GM = (N_ENT + 127) / 128;  // 782
  const int GA = (N_ENT + 63) / 64;    // 1563 aggregate blocks (64 nodes each)

  // ---- init projections (A = emb_h f32, fused split in-kernel) ----
  k_mfma_af32<false, true, false><<<dim3(GM, 2), 256, 0, stream>>>(
      emb_h, D0_, D0_, linw_h, linw_l, ent, N_ENT, D_, KP_D0, (long)D_,
      nullptr, nullptr, lin_b, nullptr);
  k_gemm_abt<8, 4><<<dim3(4, 4), 256, 0, stream>>>(rel_wt, embeT, relA, NREL_, D_,
                                                   D0_, (long)D_);

  // ================= layer 0 =================
  k_aggregate<false><<<GA, 256, 0, stream>>>(ent, relA, row_ptr, counts,
                                             csr_src, csr_et, tmp, nullptr, nullptr,
                                             part);
  k_bn_fin<<<D_, 256, 0, stream>>>(part, GA, agg_bn_g, agg_bn_b, scaleb, shiftb);
  k_mfma_af32<true, true, true><<<dim3(GM, 2), 256, 0, stream>>>(
      tmp, D_, D_, cw0_h, cw0_l, ent, N_ENT, D_, KP_D, (long)D_,
      scaleb, shiftb, concat_b, pstat);
  k_bn_fin2<<<D_, 256, 0, stream>>>(pstat, GM, cell_bn_g, cell_bn_b, scaleb, shiftb);
  // cell-BN0 not materialized: fused into layer-1 aggregate's gather
  k_gemm_abt<8, 4><<<dim3(4, 4), 256, 0, stream>>>(relA, wrT, relB, NREL_, D_, D_,
                                                   (long)D_);

  // ================= layer 1 =================
  k_aggregate<true><<<GA, 256, 0, stream>>>(ent, relB, row_ptr, counts,
                                            csr_src, csr_et, tmp, scaleb, shiftb,
                                            part);
  k_bn_fin<<<D_, 256, 0, stream>>>(part, GA, agg_bn_g + D_, agg_bn_b + D_,
                                   scaleb, shiftb);
  k_mfma_af32<true, true, true><<<dim3(GM, 2), 256, 0, stream>>>(
      tmp, D_, D_, cw1_h, cw1_l, ent, N_ENT, D_, KP_D, (long)D_,
      scaleb, shiftb, concat_b + D_, pstat);
  k_bn_fin2<<<D_, 256, 0, stream>>>(pstat, GM, cell_bn_g + D_, cell_bn_b + D_,
                                    scaleb, shiftb);
  // rel transform for the scorer
  k_gemm_abt<8, 4><<<dim3(4, 4), 256, 0, stream>>>(relB, wrT, relA, NREL_, D_, D_,
                                                   (long)D_);
  // merged: ent hi/lo split (no f32 writeback) + BN-fused q split
  k_split_all<<<NS_BLK + Q_BLK, 256, 0, stream>>>(ent, scaleb, shiftb, relA,
                                                  subj, rel, ent_h, ent_l, q_h, q_l);

  // ---- DistMult score: r17 config (255us, frozen) ----
  k_score4<<<dim3(8 * 1563), 256, 0, stream>>>(q_h, q_l, ent_h, ent_l, out);
}